// Round 10
// baseline (578.776 us; speedup 1.0000x reference)
//
#include <hip/hip_runtime.h>

typedef __attribute__((ext_vector_type(8))) short short8;
typedef __attribute__((ext_vector_type(4))) float f32x4;

#define N_NODES 1000000
#define N_UPD   200000
#define D       172
#define BM      64          // rows per GRU block
#define LDA     362         // LDS A row stride in ushorts (181 dwords, odd -> ~2-way banks)
#define KSTEPS  11          // 11 * 32 = 352 >= 344
#define NTILES  48
#define KSLICE  (NTILES*512)
#define GRU_BLOCKS (N_UPD / BM)              // 3125
#define NM4 43000000
#define BPACK_USHORTS (KSTEPS*KSLICE)        // 270336
#define BIAS_OFF  (BPACK_USHORTS*2)          // 540672 B
#define MASK_OFF  (BIAS_OFF + 688*4)         // 543424 B
#define WS_NEED   (MASK_OFF + N_NODES)

__device__ __forceinline__ unsigned short f2bf(float f) {
  union { float f; unsigned u; } v; v.f = f;
  unsigned r = v.u + 0x7FFFu + ((v.u >> 16) & 1u);
  return (unsigned short)(r >> 16);
}
__device__ __forceinline__ float bf2f(unsigned short h) {
  union { unsigned u; float f; } v; v.u = ((unsigned)h) << 16;
  return v.f;
}
__device__ __forceinline__ ushort4 f2bf4(float4 v) {
  return make_ushort4(f2bf(v.x), f2bf(v.y), f2bf(v.z), f2bf(v.w));
}

// ---------------------------------------------------------------------------
// Prep: pack B into MFMA-fragment order + fused biases + clear node mask.
// Bpack[((ks*48+nt)*64+lane)*8+e] = B[ks*32+(lane>>4)*8+e][nt*16+(lane&15)]
// nt = wc*12 + gate*3 + ti ; col j = wc*48 + ti*16 + (lane&15).
// ---------------------------------------------------------------------------
__global__ void prep_kernel(const float* __restrict__ wih, const float* __restrict__ whh,
                            const float* __restrict__ bih, const float* __restrict__ bhh,
                            unsigned short* __restrict__ Bpack, float* __restrict__ bias4,
                            uint4* __restrict__ mask16) {
  int gid = blockIdx.x * 256 + threadIdx.x;
  if (gid < 688) {
    int which = gid / 172, j = gid % 172;
    float v;
    if (which == 0)      v = bih[j]       + bhh[j];
    else if (which == 1) v = bih[172 + j] + bhh[172 + j];
    else if (which == 2) v = bih[344 + j];
    else                 v = bhh[344 + j];
    bias4[gid] = v;
  }
  if (gid < N_NODES / 16) mask16[gid] = make_uint4(0, 0, 0, 0);
  if (gid >= BPACK_USHORTS) return;
  int e  = gid & 7;
  int l  = (gid >> 3) & 63;
  int nt = (gid >> 9) % NTILES;
  int ks = gid / KSLICE;
  int k  = ks * 32 + ((l >> 4) << 3) + e;
  int c  = l & 15;
  int w  = nt / 12, tl = nt % 12;
  int gate = tl / 3, ti = tl % 3;
  int j = w * 48 + ti * 16 + c;
  float v = 0.f;
  if (j < D) {
    if (gate == 0) {
      if (k < D)        v = wih[j * D + k];
      else if (k < 2*D) v = whh[j * D + (k - D)];
    } else if (gate == 1) {
      if (k < D)        v = wih[(D + j) * D + k];
      else if (k < 2*D) v = whh[(D + j) * D + (k - D)];
    } else if (gate == 2) {
      if (k < D)        v = wih[(2*D + j) * D + k];
    } else {
      if (k >= D && k < 2*D) v = whh[(2*D + j) * D + (k - D)];
    }
  }
  Bpack[gid] = f2bf(v);
}

__global__ void mask_set_kernel(const int* __restrict__ ids, unsigned char* __restrict__ mask) {
  int i = blockIdx.x * 256 + threadIdx.x;
  if (i < N_UPD) mask[ids[i]] = 1;
}

// Full copy (fallback when ws too small for mask)
__global__ void copy_kernel(const float4* __restrict__ mem4, const float4* __restrict__ lu4,
                            float4* __restrict__ out4, float4* __restrict__ outlu4) {
  const long NL4 = N_NODES / 4;
  long stride = (long)gridDim.x * blockDim.x;
  for (long i = (long)blockIdx.x * blockDim.x + threadIdx.x; i < NM4 + NL4; i += stride) {
    if (i < NM4) out4[i] = mem4[i];
    else         outlu4[i - NM4] = lu4[i - NM4];
  }
}

// Masked copy: skip rows the GRU kernel writes. ~5.4 TB/s measured.
__global__ __launch_bounds__(256)
void copy_masked_kernel(const float4* __restrict__ mem4, const float* __restrict__ lu,
                        const unsigned char* __restrict__ mask,
                        float4* __restrict__ out4, float* __restrict__ outlu) {
  const unsigned stride = gridDim.x * 256;
  for (unsigned i = blockIdx.x * 256 + threadIdx.x; i < NM4; i += stride) {
    unsigned row = i / 43u;
    if (!mask[row]) out4[i] = mem4[i];
  }
  for (unsigned j = blockIdx.x * 256 + threadIdx.x; j < N_NODES; j += stride) {
    if (!mask[j]) outlu[j] = lu[j];
  }
}

// ---------------------------------------------------------------------------
// GRU v3: r8 structure + occupancy fix. 64 rows/block, 8 waves = 2 m-groups
// x 4 col-groups, ti-loop keeps 8 live accs (32 AGPR). launch_bounds(512,6)
// caps regs at 85 (use ~72) -> 6 waves/SIMD = 3 blocks/CU (LDS 3x46.3KB).
// LDA=362 (odd dword stride) kills the 8-way A-read bank conflict.
// ---------------------------------------------------------------------------
__global__ __launch_bounds__(512, 6)
void gru64_kernel(const float* __restrict__ memory, const float* __restrict__ msgs,
                  const int* __restrict__ ids, const float* __restrict__ ts,
                  const unsigned short* __restrict__ Bpack, const float* __restrict__ bias4,
                  float* __restrict__ out_mem, float* __restrict__ out_lu) {
  __shared__ unsigned short At[BM * LDA];   // 46336 B
  const int tid  = threadIdx.x;
  const int m0   = blockIdx.x * BM;
  const int wave = tid >> 6, lane = tid & 63;
  const int g = lane >> 4, c = lane & 15;
  const int wm = wave >> 2, wc = wave & 3;

  // ---- A staging: 64 rows x (43 x-float4 + 43 h-float4) -> bf16 LDS ----
  const float4* x4 = (const float4*)msgs + (size_t)m0 * 43;
  float4 xv[6], hv[6];
  #pragma unroll
  for (int i = 0; i < 6; ++i) {
    int s = tid + i * 512;
    if (i < 5 || s < 2752) xv[i] = x4[s];
  }
  #pragma unroll
  for (int i = 0; i < 6; ++i) {
    int s = tid + i * 512;
    if (i < 5 || s < 2752) {
      int row = s / 43, seg = s - row * 43;
      hv[i] = ((const float4*)(memory + (size_t)ids[m0 + row] * D))[seg];
    }
  }
  #pragma unroll
  for (int i = 0; i < 6; ++i) {
    int s = tid + i * 512;
    if (i < 5 || s < 2752) {
      int row = s / 43, seg = s - row * 43;
      *(ushort4*)&At[row * LDA + seg * 4]       = f2bf4(xv[i]);
      *(ushort4*)&At[row * LDA + 172 + seg * 4] = f2bf4(hv[i]);
    }
  }
  if (tid < BM) {   // zero-pad k=344..351 (352..359 never read) + lu scatter
    *(uint4*)&At[tid * LDA + 344] = make_uint4(0, 0, 0, 0);
    out_lu[ids[m0 + tid]] = ts[m0 + tid];
  }
  __syncthreads();

  const int ar0 = (wm * 32 + c) * LDA;
  const int ar1 = ar0 + 16 * LDA;
  const short8* Bp = (const short8*)Bpack;

  #pragma unroll 1
  for (int ti = 0; ti < 3; ++ti) {
    if (wc == 3 && ti == 2) continue;   // j = 176..191: all padding
    const short8* bp = Bp + (size_t)((wc * 12 + ti) * 64 + lane);

    f32x4 Cr0={0,0,0,0}, Cr1={0,0,0,0};
    f32x4 Cz0={0,0,0,0}, Cz1={0,0,0,0};
    f32x4 Ci0={0,0,0,0}, Ci1={0,0,0,0};
    f32x4 Ch0={0,0,0,0}, Ch1={0,0,0,0};

    #pragma unroll 2
    for (int ks = 0; ks < KSTEPS; ++ks) {
      short8 a0 = *(const short8*)&At[ar0 + ks * 32 + g * 8];
      short8 a1 = *(const short8*)&At[ar1 + ks * 32 + g * 8];
      const short8* bk = bp + ks * 3072;
      short8 br = bk[0];
      short8 bz = bk[192];
      short8 bi = bk[384];
      short8 bh = bk[576];
      Cr0 = __builtin_amdgcn_mfma_f32_16x16x32_bf16(a0, br, Cr0, 0, 0, 0);
      Cr1 = __builtin_amdgcn_mfma_f32_16x16x32_bf16(a1, br, Cr1, 0, 0, 0);
      Cz0 = __builtin_amdgcn_mfma_f32_16x16x32_bf16(a0, bz, Cz0, 0, 0, 0);
      Cz1 = __builtin_amdgcn_mfma_f32_16x16x32_bf16(a1, bz, Cz1, 0, 0, 0);
      Ci0 = __builtin_amdgcn_mfma_f32_16x16x32_bf16(a0, bi, Ci0, 0, 0, 0);
      Ci1 = __builtin_amdgcn_mfma_f32_16x16x32_bf16(a1, bi, Ci1, 0, 0, 0);
      Ch0 = __builtin_amdgcn_mfma_f32_16x16x32_bf16(a0, bh, Ch0, 0, 0, 0);
      Ch1 = __builtin_amdgcn_mfma_f32_16x16x32_bf16(a1, bh, Ch1, 0, 0, 0);
    }

    const int j = wc * 48 + ti * 16 + c;
    if (j < D) {
      const float b_r = bias4[j];
      const float b_z = bias4[172 + j];
      const float b_i = bias4[344 + j];
      const float b_h = bias4[516 + j];
      #pragma unroll
      for (int r = 0; r < 4; ++r) {
        {
          const int row_local = wm * 32 + g * 4 + r;
          float* orow = out_mem + (size_t)ids[m0 + row_local] * D;
          float ho = bf2f(At[row_local * LDA + 172 + j]);
          float rr = 1.f / (1.f + __expf(-(Cr0[r] + b_r)));
          float zz = 1.f / (1.f + __expf(-(Cz0[r] + b_z)));
          float e2 = __expf(2.f * (Ci0[r] + b_i + rr * (Ch0[r] + b_h)));
          float nn = 1.f - 2.f / (e2 + 1.f);
          orow[j] = nn + zz * (ho - nn);
        }
        {
          const int row_local = wm * 32 + 16 + g * 4 + r;
          float* orow = out_mem + (size_t)ids[m0 + row_local] * D;
          float ho = bf2f(At[row_local * LDA + 172 + j]);
          float rr = 1.f / (1.f + __expf(-(Cr1[r] + b_r)));
          float zz = 1.f / (1.f + __expf(-(Cz1[r] + b_z)));
          float e2 = __expf(2.f * (Ci1[r] + b_i + rr * (Ch1[r] + b_h)));
          float nn = 1.f - 2.f / (e2 + 1.f);
          orow[j] = nn + zz * (ho - nn);
        }
      }
    }
  }
}

extern "C" void kernel_launch(void* const* d_in, const int* in_sizes, int n_in,
                              void* d_out, int out_size, void* d_ws, size_t ws_size,
                              hipStream_t stream) {
  const float* memory      = (const float*)d_in[0];
  const float* last_update = (const float*)d_in[1];
  const int*   ids         = (const int*)  d_in[2];
  const float* msgs        = (const float*)d_in[3];
  const float* ts          = (const float*)d_in[4];
  const float* wih         = (const float*)d_in[5];
  const float* whh         = (const float*)d_in[6];
  const float* bih         = (const float*)d_in[7];
  const float* bhh         = (const float*)d_in[8];

  float* out_mem = (float*)d_out;
  float* out_lu  = out_mem + (size_t)N_NODES * D;

  unsigned short* Bpack = (unsigned short*)d_ws;
  float* bias4 = (float*)((char*)d_ws + BIAS_OFF);
  unsigned char* mask = (unsigned char*)d_ws + MASK_OFF;

  prep_kernel<<<BPACK_USHORTS / 256, 256, 0, stream>>>(wih, whh, bih, bhh, Bpack, bias4,
                                                       (uint4*)mask);
  if (ws_size >= WS_NEED) {
    mask_set_kernel<<<(N_UPD + 255) / 256, 256, 0, stream>>>(ids, mask);
    copy_masked_kernel<<<2048, 256, 0, stream>>>((const float4*)memory, last_update, mask,
                                                 (float4*)out_mem, out_lu);
  } else {
    copy_kernel<<<4096, 256, 0, stream>>>((const float4*)memory, (const float4*)last_update,
                                          (float4*)out_mem, (float4*)out_lu);
  }
  gru64_kernel<<<GRU_BLOCKS, 512, 0, stream>>>(memory, msgs, ids, ts, Bpack, bias4,
                                               out_mem, out_lu);
}

// Round 11
// 511.059 us; speedup vs baseline: 1.1325x; 1.1325x over previous
//
#include <hip/hip_runtime.h>

typedef __attribute__((ext_vector_type(8))) short short8;
typedef __attribute__((ext_vector_type(4))) float f32x4;

#define N_NODES 1000000
#define N_UPD   200000
#define D       172
#define BM      64          // rows per GRU block
#define LDA     360         // LDS A row stride in ushorts (720B, 16B-aligned rows)
#define KSTEPS  11          // 11 * 32 = 352 >= 344
#define NTILES  48
#define KSLICE  (NTILES*512)
#define GRU_BLOCKS (N_UPD / BM)              // 3125
#define NM4 43000000
#define BPACK_USHORTS (KSTEPS*KSLICE)        // 270336
#define BIAS_OFF  (BPACK_USHORTS*2)          // 540672 B
#define MASK_OFF  (BIAS_OFF + 688*4)         // 543424 B
#define WS_NEED   (MASK_OFF + N_NODES)

__device__ __forceinline__ unsigned short f2bf(float f) {
  union { float f; unsigned u; } v; v.f = f;
  unsigned r = v.u + 0x7FFFu + ((v.u >> 16) & 1u);
  return (unsigned short)(r >> 16);
}
__device__ __forceinline__ float bf2f(unsigned short h) {
  union { unsigned u; float f; } v; v.u = ((unsigned)h) << 16;
  return v.f;
}
__device__ __forceinline__ ushort4 f2bf4(float4 v) {
  return make_ushort4(f2bf(v.x), f2bf(v.y), f2bf(v.z), f2bf(v.w));
}

// ---------------------------------------------------------------------------
// Prep: pack B into MFMA-fragment order + fused biases + clear node mask.
// Bpack[((ks*48+nt)*64+lane)*8+e] = B[ks*32+(lane>>4)*8+e][nt*16+(lane&15)]
// nt = wc*12 + gate*3 + ti ; col j = wc*48 + ti*16 + (lane&15).
// ---------------------------------------------------------------------------
__global__ void prep_kernel(const float* __restrict__ wih, const float* __restrict__ whh,
                            const float* __restrict__ bih, const float* __restrict__ bhh,
                            unsigned short* __restrict__ Bpack, float* __restrict__ bias4,
                            uint4* __restrict__ mask16) {
  int gid = blockIdx.x * 256 + threadIdx.x;
  if (gid < 688) {
    int which = gid / 172, j = gid % 172;
    float v;
    if (which == 0)      v = bih[j]       + bhh[j];
    else if (which == 1) v = bih[172 + j] + bhh[172 + j];
    else if (which == 2) v = bih[344 + j];
    else                 v = bhh[344 + j];
    bias4[gid] = v;
  }
  if (gid < N_NODES / 16) mask16[gid] = make_uint4(0, 0, 0, 0);
  if (gid >= BPACK_USHORTS) return;
  int e  = gid & 7;
  int l  = (gid >> 3) & 63;
  int nt = (gid >> 9) % NTILES;
  int ks = gid / KSLICE;
  int k  = ks * 32 + ((l >> 4) << 3) + e;
  int c  = l & 15;
  int w  = nt / 12, tl = nt % 12;
  int gate = tl / 3, ti = tl % 3;
  int j = w * 48 + ti * 16 + c;
  float v = 0.f;
  if (j < D) {
    if (gate == 0) {
      if (k < D)        v = wih[j * D + k];
      else if (k < 2*D) v = whh[j * D + (k - D)];
    } else if (gate == 1) {
      if (k < D)        v = wih[(D + j) * D + k];
      else if (k < 2*D) v = whh[(D + j) * D + (k - D)];
    } else if (gate == 2) {
      if (k < D)        v = wih[(2*D + j) * D + k];
    } else {
      if (k >= D && k < 2*D) v = whh[(2*D + j) * D + (k - D)];
    }
  }
  Bpack[gid] = f2bf(v);
}

__global__ void mask_set_kernel(const int* __restrict__ ids, unsigned char* __restrict__ mask) {
  int i = blockIdx.x * 256 + threadIdx.x;
  if (i < N_UPD) mask[ids[i]] = 1;
}

// Full copy (fallback when ws too small for mask)
__global__ void copy_kernel(const float4* __restrict__ mem4, const float4* __restrict__ lu4,
                            float4* __restrict__ out4, float4* __restrict__ outlu4) {
  const long NL4 = N_NODES / 4;
  long stride = (long)gridDim.x * blockDim.x;
  for (long i = (long)blockIdx.x * blockDim.x + threadIdx.x; i < NM4 + NL4; i += stride) {
    if (i < NM4) out4[i] = mem4[i];
    else         outlu4[i - NM4] = lu4[i - NM4];
  }
}

// Masked copy: skip rows the GRU kernel writes.
__global__ __launch_bounds__(256)
void copy_masked_kernel(const float4* __restrict__ mem4, const float* __restrict__ lu,
                        const unsigned char* __restrict__ mask,
                        float4* __restrict__ out4, float* __restrict__ outlu) {
  const unsigned stride = gridDim.x * 256;
  for (unsigned i = blockIdx.x * 256 + threadIdx.x; i < NM4; i += stride) {
    unsigned row = i / 43u;
    if (!mask[row]) out4[i] = mem4[i];
  }
  for (unsigned j = blockIdx.x * 256 + threadIdx.x; j < N_NODES; j += stride) {
    if (!mask[j]) outlu[j] = lu[j];
  }
}

// ---------------------------------------------------------------------------
// GRU v4: 64 rows/block, 4 waves (256 thr), wave = col-group, 4 m-tiles/wave.
// One B-fragment read feeds 4 MFMAs (64 rows) -> B L2 traffic halves vs r8.
// ti-loop keeps 16 live accs (64 AGPR); reg peak ~115 -> 3 blocks/CU.
// ---------------------------------------------------------------------------
__global__ __launch_bounds__(256, 3)
void gru64_kernel(const float* __restrict__ memory, const float* __restrict__ msgs,
                  const int* __restrict__ ids, const float* __restrict__ ts,
                  const unsigned short* __restrict__ Bpack, const float* __restrict__ bias4,
                  float* __restrict__ out_mem, float* __restrict__ out_lu) {
  __shared__ unsigned short At[BM * LDA];   // 46080 B
  const int tid  = threadIdx.x;
  const int m0   = blockIdx.x * BM;
  const int wc   = tid >> 6, lane = tid & 63;
  const int g = lane >> 4, c = lane & 15;

  // ---- A staging: 2752 x-float4 then 2752 h-float4, 11 slots per phase ----
  {
    const float4* x4 = (const float4*)msgs + (size_t)m0 * 43;
    float4 xv[11];
    #pragma unroll
    for (int i = 0; i < 11; ++i) {
      int s = tid + i * 256; int sc = s < 2752 ? s : 2751;
      xv[i] = x4[sc];
    }
    #pragma unroll
    for (int i = 0; i < 11; ++i) {
      int s = tid + i * 256;
      if (s < 2752) {
        int row = s / 43, seg = s - row * 43;
        *(ushort4*)&At[row * LDA + seg * 4] = f2bf4(xv[i]);
      }
    }
    float4 hv[11];
    #pragma unroll
    for (int i = 0; i < 11; ++i) {
      int s = tid + i * 256; int sc = s < 2752 ? s : 2751;
      int row = sc / 43, seg = sc - row * 43;
      hv[i] = ((const float4*)(memory + (size_t)ids[m0 + row] * D))[seg];
    }
    #pragma unroll
    for (int i = 0; i < 11; ++i) {
      int s = tid + i * 256;
      if (s < 2752) {
        int row = s / 43, seg = s - row * 43;
        *(ushort4*)&At[row * LDA + 172 + seg * 4] = f2bf4(hv[i]);
      }
    }
  }
  if (tid < BM) {   // zero-pad k=344..351 (352..359 never read) + lu scatter
    *(uint4*)&At[tid * LDA + 344] = make_uint4(0, 0, 0, 0);
    out_lu[ids[m0 + tid]] = ts[m0 + tid];
  }
  __syncthreads();

  const int ar = c * LDA;     // m-tile mt adds mt*16*LDA
  const short8* Bp = (const short8*)Bpack;

  #pragma unroll 1
  for (int ti = 0; ti < 3; ++ti) {
    if (wc == 3 && ti == 2) continue;   // j = 176..191: all padding
    const short8* bp = Bp + (size_t)((wc * 12 + ti) * 64 + lane);

    f32x4 Cr0={0,0,0,0}, Cr1={0,0,0,0}, Cr2={0,0,0,0}, Cr3={0,0,0,0};
    f32x4 Cz0={0,0,0,0}, Cz1={0,0,0,0}, Cz2={0,0,0,0}, Cz3={0,0,0,0};
    f32x4 Ci0={0,0,0,0}, Ci1={0,0,0,0}, Ci2={0,0,0,0}, Ci3={0,0,0,0};
    f32x4 Ch0={0,0,0,0}, Ch1={0,0,0,0}, Ch2={0,0,0,0}, Ch3={0,0,0,0};

    #pragma unroll 2
    for (int ks = 0; ks < KSTEPS; ++ks) {
      const short8* bk = bp + ks * 3072;
      short8 br = bk[0];
      short8 bz = bk[192];
      short8 bi = bk[384];
      short8 bh = bk[576];
      const int ao = ar + ks * 32 + g * 8;
      short8 a0 = *(const short8*)&At[ao];
      short8 a1 = *(const short8*)&At[ao + 16 * LDA];
      short8 a2 = *(const short8*)&At[ao + 32 * LDA];
      short8 a3 = *(const short8*)&At[ao + 48 * LDA];
      Cr0 = __builtin_amdgcn_mfma_f32_16x16x32_bf16(a0, br, Cr0, 0, 0, 0);
      Cr1 = __builtin_amdgcn_mfma_f32_16x16x32_bf16(a1, br, Cr1, 0, 0, 0);
      Cr2 = __builtin_amdgcn_mfma_f32_16x16x32_bf16(a2, br, Cr2, 0, 0, 0);
      Cr3 = __builtin_amdgcn_mfma_f32_16x16x32_bf16(a3, br, Cr3, 0, 0, 0);
      Cz0 = __builtin_amdgcn_mfma_f32_16x16x32_bf16(a0, bz, Cz0, 0, 0, 0);
      Cz1 = __builtin_amdgcn_mfma_f32_16x16x32_bf16(a1, bz, Cz1, 0, 0, 0);
      Cz2 = __builtin_amdgcn_mfma_f32_16x16x32_bf16(a2, bz, Cz2, 0, 0, 0);
      Cz3 = __builtin_amdgcn_mfma_f32_16x16x32_bf16(a3, bz, Cz3, 0, 0, 0);
      Ci0 = __builtin_amdgcn_mfma_f32_16x16x32_bf16(a0, bi, Ci0, 0, 0, 0);
      Ci1 = __builtin_amdgcn_mfma_f32_16x16x32_bf16(a1, bi, Ci1, 0, 0, 0);
      Ci2 = __builtin_amdgcn_mfma_f32_16x16x32_bf16(a2, bi, Ci2, 0, 0, 0);
      Ci3 = __builtin_amdgcn_mfma_f32_16x16x32_bf16(a3, bi, Ci3, 0, 0, 0);
      Ch0 = __builtin_amdgcn_mfma_f32_16x16x32_bf16(a0, bh, Ch0, 0, 0, 0);
      Ch1 = __builtin_amdgcn_mfma_f32_16x16x32_bf16(a1, bh, Ch1, 0, 0, 0);
      Ch2 = __builtin_amdgcn_mfma_f32_16x16x32_bf16(a2, bh, Ch2, 0, 0, 0);
      Ch3 = __builtin_amdgcn_mfma_f32_16x16x32_bf16(a3, bh, Ch3, 0, 0, 0);
    }

    const int j = wc * 48 + ti * 16 + c;
    if (j < D) {
      const float b_r = bias4[j];
      const float b_z = bias4[172 + j];
      const float b_i = bias4[344 + j];
      const float b_h = bias4[516 + j];
#define DO_MT(MT, CR, CZ, CI, CH)                                                  \
      _Pragma("unroll")                                                            \
      for (int r = 0; r < 4; ++r) {                                                \
        const int row_local = (MT) * 16 + g * 4 + r;                               \
        float* orow = out_mem + (size_t)ids[m0 + row_local] * D;                   \
        float ho = bf2f(At[row_local * LDA + 172 + j]);                            \
        float rr = 1.f / (1.f + __expf(-(CR[r] + b_r)));                           \
        float zz = 1.f / (1.f + __expf(-(CZ[r] + b_z)));                           \
        float e2 = __expf(2.f * (CI[r] + b_i + rr * (CH[r] + b_h)));               \
        float nn = 1.f - 2.f / (e2 + 1.f);                                         \
        orow[j] = nn + zz * (ho - nn);                                             \
      }
      DO_MT(0, Cr0, Cz0, Ci0, Ch0)
      DO_MT(1, Cr1, Cz1, Ci1, Ch1)
      DO_MT(2, Cr2, Cz2, Ci2, Ch2)
      DO_MT(3, Cr3, Cz3, Ci3, Ch3)
#undef DO_MT
    }
  }
}

extern "C" void kernel_launch(void* const* d_in, const int* in_sizes, int n_in,
                              void* d_out, int out_size, void* d_ws, size_t ws_size,
                              hipStream_t stream) {
  const float* memory      = (const float*)d_in[0];
  const float* last_update = (const float*)d_in[1];
  const int*   ids         = (const int*)  d_in[2];
  const float* msgs        = (const float*)d_in[3];
  const float* ts          = (const float*)d_in[4];
  const float* wih         = (const float*)d_in[5];
  const float* whh         = (const float*)d_in[6];
  const float* bih         = (const float*)d_in[7];
  const float* bhh         = (const float*)d_in[8];

  float* out_mem = (float*)d_out;
  float* out_lu  = out_mem + (size_t)N_NODES * D;

  unsigned short* Bpack = (unsigned short*)d_ws;
  float* bias4 = (float*)((char*)d_ws + BIAS_OFF);
  unsigned char* mask = (unsigned char*)d_ws + MASK_OFF;

  prep_kernel<<<BPACK_USHORTS / 256, 256, 0, stream>>>(wih, whh, bih, bhh, Bpack, bias4,
                                                       (uint4*)mask);
  if (ws_size >= WS_NEED) {
    mask_set_kernel<<<(N_UPD + 255) / 256, 256, 0, stream>>>(ids, mask);
    copy_masked_kernel<<<2048, 256, 0, stream>>>((const float4*)memory, last_update, mask,
                                                 (float4*)out_mem, out_lu);
  } else {
    copy_kernel<<<4096, 256, 0, stream>>>((const float4*)memory, (const float4*)last_update,
                                          (float4*)out_mem, (float4*)out_lu);
  }
  gru64_kernel<<<GRU_BLOCKS, 256, 0, stream>>>(memory, msgs, ids, ts, Bpack, bias4,
                                               out_mem, out_lu);
}